// Round 5
// baseline (471.045 us; speedup 1.0000x reference)
//
#include <hip/hip_runtime.h>
#include <hip/hip_cooperative_groups.h>

// Masked smooth-L1 sum over 2^25 fp32 pairs -> scalar.
// R11: FUSION round. Read-structure matrix is complete (4 cells, incl. the
// canonical BabelStream-dot structure R10 = 2.7 TB/s): nt+chunked+dwordx4
// (R8) is the fastest at 3.4 TB/s and sits exactly at the apparent per-XCD
// read-return cap (~430 GB/s x 8 = 3.45 TB/s; writes are posted -> fill
// hits 6.8 TB/s; L3 hits don't lift it, R7). Read phase is AT the cap.
// Remaining slack: the 2nd dispatch + inter-kernel gap (~8-9 us). Fuse via
// cooperative launch (grid 512x1024 = 2 blocks/CU, co-resident; VGPR~36),
// keeping R8's exact per-chunk read structure (nt dwordx4, 8 in flight).
// Deterministic fixed-order reduce tree. Non-coop fallback if the launch
// is rejected under graph capture.
// Predicted: fused dispatch 80-84 us, final kernel gone, total 241-246.
// If fallback triggers: ~250 (R8-equivalent) -> declare roofline.

namespace cg = cooperative_groups;

typedef float v4f __attribute__((ext_vector_type(4)));

#define BLOCK  1024
#define GRID   512               // 2 blocks/CU -> cooperative co-residency OK
#define GROUPS 4                 // chunk-groups per block
#define CHUNK4 4096              // float4 per chunk per array
#define NWAVES (BLOCK / 64)      // 16

__device__ __forceinline__ float sl1_masked(float o, float t) {
    float d = fabsf(o - t);
    float s = (d < 1.0f) ? (0.5f * d * d) : (d - 0.5f);
    return (t != 0.0f) ? s : 0.0f;
}

__device__ __forceinline__ float sl1_v4(v4f o, v4f t) {
    return sl1_masked(o.x, t.x) + sl1_masked(o.y, t.y) +
           sl1_masked(o.z, t.z) + sl1_masked(o.w, t.w);
}

// Deterministic block sum; result valid on thread 0 only.
__device__ __forceinline__ float block_reduce_sum(float acc) {
    #pragma unroll
    for (int off = 32; off > 0; off >>= 1)
        acc += __shfl_down(acc, off, 64);
    __shared__ float wave_sums[NWAVES];
    const int lane = threadIdx.x & 63;
    const int wave = threadIdx.x >> 6;
    if (lane == 0) wave_sums[wave] = acc;
    __syncthreads();
    float s = 0.0f;
    if (threadIdx.x == 0) {
        #pragma unroll
        for (int w = 0; w < NWAVES; ++w) s += wave_sums[w];
    }
    __syncthreads();   // allow safe reuse of wave_sums by a later call
    return s;
}

__global__ __launch_bounds__(BLOCK) void sl1_fused_kernel(
    const v4f* __restrict__ o4,
    const v4f* __restrict__ t4,
    float* __restrict__ partials,
    float* __restrict__ result,
    long long n4)
{
    float acc = 0.0f;

    #pragma unroll
    for (int g = 0; g < GROUPS; ++g) {
        const long long base =
            ((long long)blockIdx.x * GROUPS + g) * CHUNK4 + threadIdx.x;
        if (base + 3LL * BLOCK < n4) {
            // R8's proven read structure: 8 nt dwordx4 loads in flight.
            v4f o[4], t[4];
            #pragma unroll
            for (int k = 0; k < 4; ++k) {
                o[k] = __builtin_nontemporal_load(&o4[base + k * BLOCK]);
                t[k] = __builtin_nontemporal_load(&t4[base + k * BLOCK]);
            }
            #pragma unroll
            for (int k = 0; k < 4; ++k)
                acc += sl1_v4(o[k], t[k]);
        } else {
            #pragma unroll
            for (int k = 0; k < 4; ++k) {
                const long long idx = base + (long long)k * BLOCK;
                if (idx < n4) {
                    v4f o = __builtin_nontemporal_load(&o4[idx]);
                    v4f t = __builtin_nontemporal_load(&t4[idx]);
                    acc += sl1_v4(o, t);
                }
            }
        }
    }

    float s = block_reduce_sum(acc);
    if (threadIdx.x == 0) partials[blockIdx.x] = s;
    __threadfence();                    // device-scope release before grid sync
    cg::this_grid().sync();

    if (blockIdx.x == 0) {
        float a2 = (threadIdx.x < GRID) ? partials[threadIdx.x] : 0.0f;
        float s2 = block_reduce_sum(a2);
        if (threadIdx.x == 0) result[0] = s2;
    }
}

// ---------- non-cooperative fallback (R8-equivalent) ----------

__global__ __launch_bounds__(BLOCK) void sl1_partial_kernel(
    const v4f* __restrict__ o4,
    const v4f* __restrict__ t4,
    float* __restrict__ partials,
    long long n4)
{
    const long long base = (long long)blockIdx.x * CHUNK4 + threadIdx.x;
    float acc = 0.0f;
    if (base + 3LL * BLOCK < n4) {
        v4f o[4], t[4];
        #pragma unroll
        for (int k = 0; k < 4; ++k) {
            o[k] = __builtin_nontemporal_load(&o4[base + k * BLOCK]);
            t[k] = __builtin_nontemporal_load(&t4[base + k * BLOCK]);
        }
        #pragma unroll
        for (int k = 0; k < 4; ++k)
            acc += sl1_v4(o[k], t[k]);
    } else {
        #pragma unroll
        for (int k = 0; k < 4; ++k) {
            const long long idx = base + (long long)k * BLOCK;
            if (idx < n4) {
                v4f o = __builtin_nontemporal_load(&o4[idx]);
                v4f t = __builtin_nontemporal_load(&t4[idx]);
                acc += sl1_v4(o, t);
            }
        }
    }
    float s = block_reduce_sum(acc);
    if (threadIdx.x == 0) partials[blockIdx.x] = s;
}

__global__ __launch_bounds__(256) void sl1_final_kernel(
    const float* __restrict__ partials,
    float* __restrict__ result,
    int n)
{
    float acc = 0.0f;
    for (int i = threadIdx.x; i < n; i += 256)
        acc += partials[i];
    #pragma unroll
    for (int off = 32; off > 0; off >>= 1)
        acc += __shfl_down(acc, off, 64);
    __shared__ float wave_sums[4];
    const int lane = threadIdx.x & 63;
    const int wave = threadIdx.x >> 6;
    if (lane == 0) wave_sums[wave] = acc;
    __syncthreads();
    if (threadIdx.x == 0)
        result[0] = wave_sums[0] + wave_sums[1] + wave_sums[2] + wave_sums[3];
}

extern "C" void kernel_launch(void* const* d_in, const int* in_sizes, int n_in,
                              void* d_out, int out_size, void* d_ws, size_t ws_size,
                              hipStream_t stream) {
    const v4f* o4 = (const v4f*)d_in[0];
    const v4f* t4 = (const v4f*)d_in[1];
    float* res      = (float*)d_out;
    float* partials = (float*)d_ws;

    const long long n  = (long long)in_sizes[0];  // 2^25
    long long n4 = n / 4;                         // 8388608 = 512 * 4 * 4096

    void* args[] = {(void*)&o4, (void*)&t4, (void*)&partials,
                    (void*)&res, (void*)&n4};
    hipError_t err = hipLaunchCooperativeKernel(
        (const void*)sl1_fused_kernel, dim3(GRID), dim3(BLOCK),
        args, 0, stream);

    if (err != hipSuccess) {
        // Fallback: classic two-dispatch path (R8-equivalent).
        const int grid2 = (int)((n4 + CHUNK4 - 1) / CHUNK4);  // 2048
        sl1_partial_kernel<<<grid2, BLOCK, 0, stream>>>(o4, t4, partials, n4);
        sl1_final_kernel<<<1, 256, 0, stream>>>(partials, res, grid2);
    }
}

// Round 7
// 431.784 us; speedup vs baseline: 1.0909x; 1.0909x over previous
//
#include <hip/hip_runtime.h>

// Masked smooth-L1 sum over 2^25 fp32 pairs -> scalar.
// R13 = R12 with compile fixes only (same theory, same prediction).
//   fix1: __hip_atomic_fence does not exist in this ROCm ->
//         __builtin_amdgcn_fence(__ATOMIC_ACQUIRE, "agent").
//         (Redundant anyway: last block's ACQ_REL fetch_add synchronizes
//         with the release sequence of all blocks' release-store+RMW.)
//   fix2: (void)hipMemsetAsync to silence nodiscard.
// Scheme: last-block-done atomic counter kills the 2nd dispatch + gap
// (~6 us) WITHOUT cooperative launch (R11 proved grid.sync coherence mode
// slows the whole read loop 3.5x). Read phase = R8's proven structure
// (nt dwordx4, 8 in flight, BLOCK=1024, CHUNK=4096, grid=2048), which sits
// at the calibrated ~3.45 TB/s read-return cap (R10 BabelStream-dot port
// benched slower on the same chip).
// Predicted: onepass 82-85 us, final kernel gone, memset +1-2 us,
// total 244-248. If >=250: revert to R8, declare roofline.

typedef float v4f __attribute__((ext_vector_type(4)));

#define BLOCK  1024
#define ITERS  4
#define CHUNK  (BLOCK * ITERS)   // 4096 float4 per block per array
#define NWAVES (BLOCK / 64)      // 16
#define NGRID  2048              // 8388608 / 4096

__device__ __forceinline__ float sl1_masked(float o, float t) {
    float d = fabsf(o - t);
    float s = (d < 1.0f) ? (0.5f * d * d) : (d - 0.5f);
    return (t != 0.0f) ? s : 0.0f;
}

__device__ __forceinline__ float sl1_v4(v4f o, v4f t) {
    return sl1_masked(o.x, t.x) + sl1_masked(o.y, t.y) +
           sl1_masked(o.z, t.z) + sl1_masked(o.w, t.w);
}

// Deterministic block sum; result valid on thread 0 only.
__device__ __forceinline__ float block_reduce_sum(float acc) {
    #pragma unroll
    for (int off = 32; off > 0; off >>= 1)
        acc += __shfl_down(acc, off, 64);
    __shared__ float wave_sums[NWAVES];
    const int lane = threadIdx.x & 63;
    const int wave = threadIdx.x >> 6;
    if (lane == 0) wave_sums[wave] = acc;
    __syncthreads();
    float s = 0.0f;
    if (threadIdx.x == 0) {
        #pragma unroll
        for (int w = 0; w < NWAVES; ++w) s += wave_sums[w];
    }
    return s;
}

__global__ __launch_bounds__(BLOCK) void sl1_onepass_kernel(
    const v4f* __restrict__ o4,
    const v4f* __restrict__ t4,
    float* __restrict__ partials,
    unsigned int* __restrict__ counter,   // pre-zeroed by hipMemsetAsync
    float* __restrict__ result,
    long long n4)
{
    const long long base = (long long)blockIdx.x * CHUNK + threadIdx.x;
    float acc = 0.0f;

    if (base + (ITERS - 1) * BLOCK < n4) {
        // R8's proven read structure: 8 nt dwordx4 loads in flight.
        v4f o[ITERS], t[ITERS];
        #pragma unroll
        for (int k = 0; k < ITERS; ++k) {
            o[k] = __builtin_nontemporal_load(&o4[base + k * BLOCK]);
            t[k] = __builtin_nontemporal_load(&t4[base + k * BLOCK]);
        }
        #pragma unroll
        for (int k = 0; k < ITERS; ++k)
            acc += sl1_v4(o[k], t[k]);
    } else {
        #pragma unroll
        for (int k = 0; k < ITERS; ++k) {
            long long idx = base + (long long)k * BLOCK;
            if (idx < n4) {
                v4f o = __builtin_nontemporal_load(&o4[idx]);
                v4f t = __builtin_nontemporal_load(&t4[idx]);
                acc += sl1_v4(o, t);
            }
        }
    }

    float s = block_reduce_sum(acc);

    // Publish this block's partial at agent scope, then arrive.
    __shared__ bool is_last;
    if (threadIdx.x == 0) {
        __hip_atomic_store(&partials[blockIdx.x], s,
                           __ATOMIC_RELEASE, __HIP_MEMORY_SCOPE_AGENT);
        unsigned int prev = __hip_atomic_fetch_add(
            counter, 1u, __ATOMIC_ACQ_REL, __HIP_MEMORY_SCOPE_AGENT);
        is_last = (prev == NGRID - 1);
    }
    __syncthreads();

    if (is_last) {
        // Fixed-order tree: identical summation order no matter which
        // block executes this -> bitwise deterministic.
        __builtin_amdgcn_fence(__ATOMIC_ACQUIRE, "agent");
        float a = __hip_atomic_load(&partials[threadIdx.x],
                                    __ATOMIC_RELAXED, __HIP_MEMORY_SCOPE_AGENT)
                + __hip_atomic_load(&partials[threadIdx.x + BLOCK],
                                    __ATOMIC_RELAXED, __HIP_MEMORY_SCOPE_AGENT);
        float s2 = block_reduce_sum(a);
        if (threadIdx.x == 0) result[0] = s2;
    }
}

extern "C" void kernel_launch(void* const* d_in, const int* in_sizes, int n_in,
                              void* d_out, int out_size, void* d_ws, size_t ws_size,
                              hipStream_t stream) {
    const v4f* o4 = (const v4f*)d_in[0];
    const v4f* t4 = (const v4f*)d_in[1];
    float* res      = (float*)d_out;
    float* partials = (float*)d_ws;
    unsigned int* counter = (unsigned int*)(partials + NGRID);

    const long long n  = (long long)in_sizes[0];  // 2^25
    const long long n4 = n / 4;                   // 8388608 = 2048 * 4096

    (void)hipMemsetAsync(counter, 0, sizeof(unsigned int), stream);
    sl1_onepass_kernel<<<NGRID, BLOCK, 0, stream>>>(
        o4, t4, partials, counter, res, n4);
}

// Round 8
// 254.376 us; speedup vs baseline: 1.8518x; 1.6974x over previous
//
#include <hip/hip_runtime.h>

// Masked smooth-L1 sum over 2^25 fp32 pairs -> scalar.
// R14: single-variable test of the wbl2 theory. R13 (release store +
// acq_rel RMW per block) ran 232 us vs R8's 79 with identical traffic ->
// fixed cost, matching R11's cooperative 282 us. Mechanism per LLVM
// gfx940+ memory model: RELEASE-ordered agent-scope accesses emit
// buffer_wbl2 sc1 (L2 writeback) each time -> 4096 L2-drains/kernel,
// interfering with the streaming reads (per-XCD L2s non-coherent).
// Fix: RELAXED agent-scope atomics only (sc1 bit, straight to the
// XCD-shared memory-side coherence point; NO cache maintenance), with
// visibility ordered manually:
//   block: store partial (relaxed,agent) -> s_waitcnt vmcnt(0) ->
//          fetch_add counter (relaxed,agent)
//   last block (prev==2047): all 2048 stores have provably reached the
//          coherence point -> read partials (relaxed,agent), fixed-order
//          tree reduce (bitwise deterministic), write result.
// Read phase = R8's proven structure, untouched.
// Predicted: onepass 82-88 us, total 242-248. If still >=150 us: penalty
// is agent-atomics per se -> revert R8, declare roofline.

typedef float v4f __attribute__((ext_vector_type(4)));

#define BLOCK  1024
#define ITERS  4
#define CHUNK  (BLOCK * ITERS)   // 4096 float4 per block per array
#define NWAVES (BLOCK / 64)      // 16
#define NGRID  2048              // 8388608 / 4096

__device__ __forceinline__ float sl1_masked(float o, float t) {
    float d = fabsf(o - t);
    float s = (d < 1.0f) ? (0.5f * d * d) : (d - 0.5f);
    return (t != 0.0f) ? s : 0.0f;
}

__device__ __forceinline__ float sl1_v4(v4f o, v4f t) {
    return sl1_masked(o.x, t.x) + sl1_masked(o.y, t.y) +
           sl1_masked(o.z, t.z) + sl1_masked(o.w, t.w);
}

// Deterministic block sum; result valid on thread 0 only.
__device__ __forceinline__ float block_reduce_sum(float acc) {
    #pragma unroll
    for (int off = 32; off > 0; off >>= 1)
        acc += __shfl_down(acc, off, 64);
    __shared__ float wave_sums[NWAVES];
    const int lane = threadIdx.x & 63;
    const int wave = threadIdx.x >> 6;
    if (lane == 0) wave_sums[wave] = acc;
    __syncthreads();
    float s = 0.0f;
    if (threadIdx.x == 0) {
        #pragma unroll
        for (int w = 0; w < NWAVES; ++w) s += wave_sums[w];
    }
    return s;
}

__global__ __launch_bounds__(BLOCK) void sl1_onepass_kernel(
    const v4f* __restrict__ o4,
    const v4f* __restrict__ t4,
    float* __restrict__ partials,
    unsigned int* __restrict__ counter,   // pre-zeroed by hipMemsetAsync
    float* __restrict__ result,
    long long n4)
{
    const long long base = (long long)blockIdx.x * CHUNK + threadIdx.x;
    float acc = 0.0f;

    if (base + (ITERS - 1) * BLOCK < n4) {
        // R8's proven read structure: 8 nt dwordx4 loads in flight.
        v4f o[ITERS], t[ITERS];
        #pragma unroll
        for (int k = 0; k < ITERS; ++k) {
            o[k] = __builtin_nontemporal_load(&o4[base + k * BLOCK]);
            t[k] = __builtin_nontemporal_load(&t4[base + k * BLOCK]);
        }
        #pragma unroll
        for (int k = 0; k < ITERS; ++k)
            acc += sl1_v4(o[k], t[k]);
    } else {
        #pragma unroll
        for (int k = 0; k < ITERS; ++k) {
            long long idx = base + (long long)k * BLOCK;
            if (idx < n4) {
                v4f o = __builtin_nontemporal_load(&o4[idx]);
                v4f t = __builtin_nontemporal_load(&t4[idx]);
                acc += sl1_v4(o, t);
            }
        }
    }

    float s = block_reduce_sum(acc);

    // Publish partial with RELAXED agent atomics only (sc1 -> coherence
    // point; no buffer_wbl2). Manual ordering: drain the store before the
    // counter increment so prev==2047 implies all partials are visible.
    __shared__ bool is_last;
    if (threadIdx.x == 0) {
        __hip_atomic_store(&partials[blockIdx.x], s,
                           __ATOMIC_RELAXED, __HIP_MEMORY_SCOPE_AGENT);
        asm volatile("s_waitcnt vmcnt(0)" ::: "memory");
        unsigned int prev = __hip_atomic_fetch_add(
            counter, 1u, __ATOMIC_RELAXED, __HIP_MEMORY_SCOPE_AGENT);
        is_last = (prev == NGRID - 1);
    }
    __syncthreads();

    if (is_last) {
        // Fixed-order tree: identical summation order no matter which
        // block executes this -> bitwise deterministic.
        float a = __hip_atomic_load(&partials[threadIdx.x],
                                    __ATOMIC_RELAXED, __HIP_MEMORY_SCOPE_AGENT)
                + __hip_atomic_load(&partials[threadIdx.x + BLOCK],
                                    __ATOMIC_RELAXED, __HIP_MEMORY_SCOPE_AGENT);
        float s2 = block_reduce_sum(a);
        if (threadIdx.x == 0) result[0] = s2;
    }
}

extern "C" void kernel_launch(void* const* d_in, const int* in_sizes, int n_in,
                              void* d_out, int out_size, void* d_ws, size_t ws_size,
                              hipStream_t stream) {
    const v4f* o4 = (const v4f*)d_in[0];
    const v4f* t4 = (const v4f*)d_in[1];
    float* res      = (float*)d_out;
    float* partials = (float*)d_ws;
    unsigned int* counter = (unsigned int*)(partials + NGRID);

    const long long n  = (long long)in_sizes[0];  // 2^25
    const long long n4 = n / 4;                   // 8388608 = 2048 * 4096

    (void)hipMemsetAsync(counter, 0, sizeof(unsigned int), stream);
    sl1_onepass_kernel<<<NGRID, BLOCK, 0, stream>>>(
        o4, t4, partials, counter, res, n4);
}

// Round 9
// 252.319 us; speedup vs baseline: 1.8669x; 1.0082x over previous
//
#include <hip/hip_runtime.h>

// Masked smooth-L1 sum over 2^25 fp32 pairs -> scalar.
// R15: REVERT to R8 verbatim — the best measured configuration (249.5 us).
// Session findings baked in:
//  - Read structure: nt + chunked + dwordx4, 8 loads in flight, BLOCK=1024.
//    Fastest of 5 structures tried (plain-x4 2.4 TB/s, scalar grid-stride
//    [canonical BabelStream-dot port] 2.7 TB/s, nt-x4 3.4-3.5 TB/s).
//  - 3.45 TB/s is a read-return-path cap: L3-hit reads are no faster (R7,
//    FETCH=134MB proves one array is always L3-served), fill writes hit
//    6.8 TB/s (posted), and the external known-good structure can't beat it.
//  - Fusion is net-neutral-to-negative: cooperative launch poisons the
//    whole kernel (282 us; grid.sync coherence mode), release/acq_rel
//    agent atomics cost ~150 us (per-occurrence L2 writebacks on gfx950),
//    relaxed agent atomics + manual vmcnt ordering work (kernel ~77 us)
//    but the extra memset dispatch + serial tail eat the saved ~6 us.
// Two-dispatch layout: 2048-block partial kernel + 1-block final reduce.
// Expected: partial 77-79 us, FETCH ~134 MB, total ~248-252.

typedef float v4f __attribute__((ext_vector_type(4)));

#define BLOCK 1024
#define ITERS 4
#define CHUNK (BLOCK * ITERS)    // 4096 float4 per block per array
#define NWAVES (BLOCK / 64)      // 16

__device__ __forceinline__ float sl1_masked(float o, float t) {
    float d = fabsf(o - t);
    float s = (d < 1.0f) ? (0.5f * d * d) : (d - 0.5f);
    return (t != 0.0f) ? s : 0.0f;
}

__device__ __forceinline__ float sl1_v4(v4f o, v4f t) {
    return sl1_masked(o.x, t.x) + sl1_masked(o.y, t.y) +
           sl1_masked(o.z, t.z) + sl1_masked(o.w, t.w);
}

__global__ __launch_bounds__(BLOCK) void sl1_partial_kernel(
    const v4f* __restrict__ o4,
    const v4f* __restrict__ t4,
    float* __restrict__ partials,
    long long n4)
{
    const long long base = (long long)blockIdx.x * CHUNK + threadIdx.x;
    float acc = 0.0f;

    if (base + (ITERS - 1) * BLOCK < n4) {
        // Fast path: issue all 8 nt loads up front (true MLP), then consume.
        v4f o[ITERS], t[ITERS];
        #pragma unroll
        for (int k = 0; k < ITERS; ++k) {
            o[k] = __builtin_nontemporal_load(&o4[base + k * BLOCK]);
            t[k] = __builtin_nontemporal_load(&t4[base + k * BLOCK]);
        }
        #pragma unroll
        for (int k = 0; k < ITERS; ++k)
            acc += sl1_v4(o[k], t[k]);
    } else {
        #pragma unroll
        for (int k = 0; k < ITERS; ++k) {
            long long idx = base + (long long)k * BLOCK;
            if (idx < n4) {
                v4f o = __builtin_nontemporal_load(&o4[idx]);
                v4f t = __builtin_nontemporal_load(&t4[idx]);
                acc += sl1_v4(o, t);
            }
        }
    }

    // Block reduction: wave shuffle-reduce, then serial sum of 16 wave
    // partials in fixed order (deterministic).
    #pragma unroll
    for (int off = 32; off > 0; off >>= 1)
        acc += __shfl_down(acc, off, 64);
    __shared__ float wave_sums[NWAVES];
    const int lane = threadIdx.x & 63;
    const int wave = threadIdx.x >> 6;
    if (lane == 0) wave_sums[wave] = acc;
    __syncthreads();
    if (threadIdx.x == 0) {
        float s = 0.0f;
        #pragma unroll
        for (int w = 0; w < NWAVES; ++w) s += wave_sums[w];
        partials[blockIdx.x] = s;
    }
}

__global__ __launch_bounds__(256) void sl1_final_kernel(
    const float* __restrict__ partials,
    float* __restrict__ result,
    int n)
{
    float acc = 0.0f;
    for (int i = threadIdx.x; i < n; i += 256)
        acc += partials[i];
    #pragma unroll
    for (int off = 32; off > 0; off >>= 1)
        acc += __shfl_down(acc, off, 64);
    __shared__ float wave_sums[4];
    const int lane = threadIdx.x & 63;
    const int wave = threadIdx.x >> 6;
    if (lane == 0) wave_sums[wave] = acc;
    __syncthreads();
    if (threadIdx.x == 0)
        result[0] = wave_sums[0] + wave_sums[1] + wave_sums[2] + wave_sums[3];
}

extern "C" void kernel_launch(void* const* d_in, const int* in_sizes, int n_in,
                              void* d_out, int out_size, void* d_ws, size_t ws_size,
                              hipStream_t stream) {
    const v4f* o4 = (const v4f*)d_in[0];
    const v4f* t4 = (const v4f*)d_in[1];
    float* res      = (float*)d_out;
    float* partials = (float*)d_ws;

    const long long n  = (long long)in_sizes[0];  // 2^25
    const long long n4 = n / 4;                   // 8388608 = 2048 * 4096

    const int grid = (int)((n4 + CHUNK - 1) / CHUNK);  // 2048
    sl1_partial_kernel<<<grid, BLOCK, 0, stream>>>(o4, t4, partials, n4);
    sl1_final_kernel<<<1, 256, 0, stream>>>(partials, res, grid);
}